// Round 1
// baseline (1887.133 us; speedup 1.0000x reference)
//
#include <hip/hip_runtime.h>
#include <hip/hip_bf16.h>
#include <math.h>

#define N_NODES 50000
#define N_EDGES 800000
#define DIM 256
#define HEADS 8
// per-head value width = 2*HD = 32
#define LAMBDA_INIT 0.63212055882855767f

// ---------- helpers: monotonic float<->uint mapping for atomicMax on floats ----------
__device__ __forceinline__ unsigned f2ord(float f) {
    unsigned u = __float_as_uint(f);
    return (u & 0x80000000u) ? ~u : (u | 0x80000000u);
}
__device__ __forceinline__ float ord2f(unsigned o) {
    unsigned u = (o & 0x80000000u) ? (o & 0x7fffffffu) : ~o;
    return __uint_as_float(u);
}
#define ORD_NEG_INF 0x007fffffu   // f2ord(-inf)

// ---------- beta = sigmoid(exp(dot(lq,lk)) * LAMBDA_INIT) ----------
__global__ void beta_kernel(const float* __restrict__ lq, const float* __restrict__ lk,
                            float* __restrict__ beta_ws, float* __restrict__ beta_out) {
    __shared__ float red[128];
    float v = 0.f;
    for (int i = threadIdx.x; i < 100; i += 128) v += lq[i] * lk[i];
    red[threadIdx.x] = v;
    __syncthreads();
    for (int s = 64; s > 0; s >>= 1) {
        if (threadIdx.x < s) red[threadIdx.x] += red[threadIdx.x + s];
        __syncthreads();
    }
    if (threadIdx.x == 0) {
        float l1 = expf(red[0]);
        float b = 1.f / (1.f + expf(-l1 * LAMBDA_INIT));
        *beta_ws = b;
        *beta_out = b;
    }
}

// ---------- init m buffer to ord(-inf) ----------
__global__ void init_m(unsigned* __restrict__ mbuf, int n) {
    int i = blockIdx.x * blockDim.x + threadIdx.x;
    if (i < n) mbuf[i] = ORD_NEG_INF;
}

// ---------- C[m,j] = sum_k A[m,k] * W[j,k]   (A:[M,256], W:[256,256], C:[M,256]) ----------
__global__ __launch_bounds__(256) void gemm_nt64(const float* __restrict__ A,
                                                 const float* __restrict__ W,
                                                 float* __restrict__ C, int M) {
    const int K = 256;
    __shared__ float As[16][65];
    __shared__ float Ws[16][65];
    int tid = threadIdx.x;
    int bm = blockIdx.x * 64;
    int bj = blockIdx.y * 64;
    int tx = tid % 16, ty = tid / 16;
    float acc[4][4] = {};
    int lr = tid / 4;          // 0..63: row within tile
    int lk4 = (tid % 4) * 4;   // k sub-offset 0/4/8/12

    for (int k0 = 0; k0 < K; k0 += 16) {
        int m = bm + lr;
        float4 av = (m < M) ? *(const float4*)&A[(size_t)m * K + k0 + lk4]
                            : make_float4(0.f, 0.f, 0.f, 0.f);
        As[lk4 + 0][lr] = av.x; As[lk4 + 1][lr] = av.y;
        As[lk4 + 2][lr] = av.z; As[lk4 + 3][lr] = av.w;
        int j = bj + lr;
        float4 wv = *(const float4*)&W[(size_t)j * K + k0 + lk4];
        Ws[lk4 + 0][lr] = wv.x; Ws[lk4 + 1][lr] = wv.y;
        Ws[lk4 + 2][lr] = wv.z; Ws[lk4 + 3][lr] = wv.w;
        __syncthreads();
#pragma unroll
        for (int kk = 0; kk < 16; ++kk) {
            float a0[4], w0[4];
#pragma unroll
            for (int r = 0; r < 4; ++r) a0[r] = As[kk][ty * 4 + r];
#pragma unroll
            for (int c = 0; c < 4; ++c) w0[c] = Ws[kk][tx * 4 + c];
#pragma unroll
            for (int r = 0; r < 4; ++r)
#pragma unroll
                for (int c = 0; c < 4; ++c) acc[r][c] += a0[r] * w0[c];
        }
        __syncthreads();
    }
#pragma unroll
    for (int r = 0; r < 4; ++r) {
        int m = bm + ty * 4 + r;
        if (m < M) {
#pragma unroll
            for (int c = 0; c < 4; ++c)
                C[(size_t)m * 256 + bj + tx * 4 + c] = acc[r][c];
        }
    }
}

// ---------- edge MLP: scores[e, i] (i = h*2+c) + atomicMax into mbuf ----------
__global__ __launch_bounds__(256) void edge_mlp(const float* __restrict__ edge_attr,
                                                const float* __restrict__ e_w1,
                                                const float* __restrict__ e_b1,
                                                const float* __restrict__ e_w2,
                                                const float* __restrict__ e_b2,
                                                const int* __restrict__ tgt,
                                                float* __restrict__ scores,
                                                unsigned* __restrict__ mbuf) {
    __shared__ float w1s[256 * 6];
    __shared__ float b1s[256];
    __shared__ float w2s[16 * 256];
    __shared__ float b2s[16];
    for (int i = threadIdx.x; i < 256 * 6; i += 256) w1s[i] = e_w1[i];
    b1s[threadIdx.x] = e_b1[threadIdx.x];
    for (int i = threadIdx.x; i < 16 * 256; i += 256) w2s[i] = e_w2[i];
    if (threadIdx.x < 16) b2s[threadIdx.x] = e_b2[threadIdx.x];
    __syncthreads();

    int e = blockIdx.x * 256 + threadIdx.x;
    if (e >= N_EDGES) return;
    float ea[6];
#pragma unroll
    for (int k = 0; k < 6; ++k) ea[k] = edge_attr[(size_t)e * 6 + k];
    float acc[16];
#pragma unroll
    for (int i = 0; i < 16; ++i) acc[i] = 0.f;
    for (int j = 0; j < 256; ++j) {
        float h = b1s[j];
#pragma unroll
        for (int k = 0; k < 6; ++k) h += ea[k] * w1s[j * 6 + k];
        // exact GELU: x * 0.5 * (1 + erf(x/sqrt(2)))
        h = 0.5f * h * (1.f + erff(h * 0.70710678118654752f));
#pragma unroll
        for (int i = 0; i < 16; ++i) acc[i] += h * w2s[i * 256 + j];
    }
    int t = tgt[e];
#pragma unroll
    for (int i = 0; i < 16; ++i) {
        float sc = acc[i] + b2s[i];
        scores[(size_t)e * 16 + i] = sc;
        atomicMax(&mbuf[t * 16 + i], f2ord(sc));
    }
}

// ---------- e = exp(score - m[tgt]); atomicAdd into sbuf; overwrite scores with e ----------
__global__ __launch_bounds__(256) void exp_sum(const int* __restrict__ tgt,
                                               float* __restrict__ scores,
                                               const unsigned* __restrict__ mbuf,
                                               float* __restrict__ sbuf) {
    int idx = blockIdx.x * 256 + threadIdx.x;
    if (idx >= N_EDGES * 16) return;
    int e = idx >> 4, i = idx & 15;
    int t = tgt[e];
    float m = ord2f(mbuf[t * 16 + i]);
    float ex = expf(scores[idx] - m);
    scores[idx] = ex;
    atomicAdd(&sbuf[t * 16 + i], ex);
}

// ---------- per (edge, head): w = e1/s1 - beta*e2/s2; scatter w * V[src] ----------
__global__ __launch_bounds__(256) void scatter_v(const int* __restrict__ srcp,
                                                 const int* __restrict__ tgtp,
                                                 const float* __restrict__ scores, // holds exp()
                                                 const float* __restrict__ sbuf,
                                                 const float* __restrict__ V,
                                                 const float* __restrict__ betap,
                                                 float* __restrict__ accum,
                                                 float* __restrict__ attn_out) {
    long gid = (long)blockIdx.x * 256 + threadIdx.x;
    int p = (int)(gid >> 5);       // (edge, head) pair
    int lane = (int)(gid & 31);
    if (p >= N_EDGES * HEADS) return;
    int e = p >> 3, h = p & 7;
    int s = srcp[e], t = tgtp[e];
    float beta = *betap;
    float e1 = scores[(size_t)e * 16 + 2 * h];
    float e2 = scores[(size_t)e * 16 + 2 * h + 1];
    float s1 = sbuf[t * 16 + 2 * h];
    float s2 = sbuf[t * 16 + 2 * h + 1];
    float w = e1 / s1 - beta * (e2 / s2);
    if (lane == 0) attn_out[(size_t)e * 8 + h] = w;
    float v = V[(size_t)s * 256 + h * 32 + lane];
    atomicAdd(&accum[(size_t)t * 256 + h * 32 + lane], w * v);
}

extern "C" void kernel_launch(void* const* d_in, const int* in_sizes, int n_in,
                              void* d_out, int out_size, void* d_ws, size_t ws_size,
                              hipStream_t stream) {
    const float* x         = (const float*)d_in[0];
    const float* edge_attr = (const float*)d_in[1];
    const float* v_w       = (const float*)d_in[2];
    const float* out_w     = (const float*)d_in[3];
    const float* e_w1      = (const float*)d_in[4];
    const float* e_b1      = (const float*)d_in[5];
    const float* e_w2      = (const float*)d_in[6];
    const float* e_b2      = (const float*)d_in[7];
    const float* lq        = (const float*)d_in[8];
    const float* lk        = (const float*)d_in[9];
    const int*   ei        = (const int*)d_in[10];
    const int* srcp = ei;
    const int* tgtp = ei + N_EDGES;

    float* out = (float*)d_out;                      // [N*256] out, [E*8] attn, [1] beta
    float* attn_out = out + (size_t)N_NODES * 256;
    float* beta_out = attn_out + (size_t)N_EDGES * 8;

    // workspace layout (floats)
    float*    V      = (float*)d_ws;                       // 12.8M
    float*    scores = V + (size_t)N_NODES * 256;          // 12.8M
    unsigned* mbuf   = (unsigned*)(scores + (size_t)N_EDGES * 16);  // 800K
    float*    sbuf   = (float*)(mbuf + (size_t)N_NODES * 16);       // 800K
    float*    accum  = sbuf + (size_t)N_NODES * 16;        // 12.8M
    float*    betap  = accum + (size_t)N_NODES * 256;      // 1

    // 1. beta (also writes d_out beta slot)
    beta_kernel<<<1, 128, 0, stream>>>(lq, lk, betap, beta_out);

    // 2. init segment buffers
    hipMemsetAsync(sbuf, 0, (size_t)N_NODES * 16 * sizeof(float), stream);
    hipMemsetAsync(accum, 0, (size_t)N_NODES * 256 * sizeof(float), stream);
    init_m<<<(N_NODES * 16 + 255) / 256, 256, 0, stream>>>(mbuf, N_NODES * 16);

    // 3. V = x @ v_w.T
    gemm_nt64<<<dim3((N_NODES + 63) / 64, 4), 256, 0, stream>>>(x, v_w, V, N_NODES);

    // 4. edge MLP -> scores, segment max
    edge_mlp<<<N_EDGES / 256, 256, 0, stream>>>(edge_attr, e_w1, e_b1, e_w2, e_b2,
                                                tgtp, scores, mbuf);

    // 5. exp + segment sum
    exp_sum<<<(N_EDGES * 16 + 255) / 256, 256, 0, stream>>>(tgtp, scores, mbuf, sbuf);

    // 6. attention weights + weighted scatter of V
    scatter_v<<<N_EDGES, 256, 0, stream>>>(srcp, tgtp, scores, sbuf, V, betap,
                                           accum, attn_out);

    // 7. out = accum @ out_w.T
    gemm_nt64<<<dim3((N_NODES + 63) / 64, 4), 256, 0, stream>>>(accum, out_w, out, N_NODES);
}

// Round 2
// 973.850 us; speedup vs baseline: 1.9378x; 1.9378x over previous
//
#include <hip/hip_runtime.h>
#include <hip/hip_bf16.h>
#include <math.h>

#define N_NODES 50000
#define N_EDGES 800000
#define DIM 256
#define HEADS 8
#define LAMBDA_INIT 0.63212055882855767f

// ---------- beta = sigmoid(exp(dot(lq,lk)) * LAMBDA_INIT) ----------
__global__ void beta_kernel(const float* __restrict__ lq, const float* __restrict__ lk,
                            float* __restrict__ beta_ws, float* __restrict__ beta_out) {
    __shared__ float red[128];
    float v = 0.f;
    for (int i = threadIdx.x; i < 100; i += 128) v += lq[i] * lk[i];
    red[threadIdx.x] = v;
    __syncthreads();
    for (int s = 64; s > 0; s >>= 1) {
        if (threadIdx.x < s) red[threadIdx.x] += red[threadIdx.x + s];
        __syncthreads();
    }
    if (threadIdx.x == 0) {
        float l1 = expf(red[0]);
        float b = 1.f / (1.f + expf(-l1 * LAMBDA_INIT));
        *beta_ws = b;
        *beta_out = b;
    }
}

// ---------- histogram of tgt ----------
__global__ __launch_bounds__(256) void hist_kernel(const int* __restrict__ tgt,
                                                   int* __restrict__ cnt) {
    int e = blockIdx.x * 256 + threadIdx.x;
    if (e < N_EDGES) atomicAdd(&cnt[tgt[e]], 1);
}

// ---------- 3-kernel exclusive scan over cnt[N_NODES] ----------
__global__ __launch_bounds__(256) void scan1(const int* __restrict__ cnt,
                                             int* __restrict__ offs,
                                             int* __restrict__ partials, int n) {
    __shared__ int sh[256];
    int i = blockIdx.x * 256 + threadIdx.x;
    int v = (i < n) ? cnt[i] : 0;
    sh[threadIdx.x] = v;
    __syncthreads();
    for (int s = 1; s < 256; s <<= 1) {
        int add = (threadIdx.x >= s) ? sh[threadIdx.x - s] : 0;
        __syncthreads();
        sh[threadIdx.x] += add;
        __syncthreads();
    }
    if (i < n) offs[i] = sh[threadIdx.x] - v;          // exclusive
    if (threadIdx.x == 255) partials[blockIdx.x] = sh[255];
}

__global__ __launch_bounds__(256) void scan2(int* __restrict__ partials, int nb) {
    __shared__ int sh[256];
    int v = (threadIdx.x < nb) ? partials[threadIdx.x] : 0;
    sh[threadIdx.x] = v;
    __syncthreads();
    for (int s = 1; s < 256; s <<= 1) {
        int add = (threadIdx.x >= s) ? sh[threadIdx.x - s] : 0;
        __syncthreads();
        sh[threadIdx.x] += add;
        __syncthreads();
    }
    if (threadIdx.x < nb) partials[threadIdx.x] = sh[threadIdx.x] - v;  // exclusive
}

__global__ __launch_bounds__(256) void scan3(int* __restrict__ offs,
                                             const int* __restrict__ partials,
                                             int* __restrict__ cursor, int n) {
    int i = blockIdx.x * 256 + threadIdx.x;
    if (i < n) {
        int o = offs[i] + partials[blockIdx.x];
        offs[i] = o;
        cursor[i] = o;
    }
    if (i == 0) offs[n] = N_EDGES;
}

// ---------- scatter edge ids into per-node buckets ----------
__global__ __launch_bounds__(256) void scatter_eid(const int* __restrict__ tgt,
                                                   int* __restrict__ cursor,
                                                   int* __restrict__ sorted_eid) {
    int e = blockIdx.x * 256 + threadIdx.x;
    if (e < N_EDGES) {
        int p = atomicAdd(&cursor[tgt[e]], 1);
        sorted_eid[p] = e;
    }
}

// ---------- C[m,j] = sum_k A[m,k] * W[j,k]   (A:[M,256], W:[256,256], C:[M,256]) ----------
__global__ __launch_bounds__(256) void gemm_nt64(const float* __restrict__ A,
                                                 const float* __restrict__ W,
                                                 float* __restrict__ C, int M) {
    const int K = 256;
    __shared__ float As[16][65];
    __shared__ float Ws[16][65];
    int tid = threadIdx.x;
    int bm = blockIdx.x * 64;
    int bj = blockIdx.y * 64;
    int tx = tid % 16, ty = tid / 16;
    float acc[4][4] = {};
    int lr = tid / 4;
    int lk4 = (tid % 4) * 4;

    for (int k0 = 0; k0 < K; k0 += 16) {
        int m = bm + lr;
        float4 av = (m < M) ? *(const float4*)&A[(size_t)m * K + k0 + lk4]
                            : make_float4(0.f, 0.f, 0.f, 0.f);
        As[lk4 + 0][lr] = av.x; As[lk4 + 1][lr] = av.y;
        As[lk4 + 2][lr] = av.z; As[lk4 + 3][lr] = av.w;
        int j = bj + lr;
        float4 wv = *(const float4*)&W[(size_t)j * K + k0 + lk4];
        Ws[lk4 + 0][lr] = wv.x; Ws[lk4 + 1][lr] = wv.y;
        Ws[lk4 + 2][lr] = wv.z; Ws[lk4 + 3][lr] = wv.w;
        __syncthreads();
#pragma unroll
        for (int kk = 0; kk < 16; ++kk) {
            float a0[4], w0[4];
#pragma unroll
            for (int r = 0; r < 4; ++r) a0[r] = As[kk][ty * 4 + r];
#pragma unroll
            for (int c = 0; c < 4; ++c) w0[c] = Ws[kk][tx * 4 + c];
#pragma unroll
            for (int r = 0; r < 4; ++r)
#pragma unroll
                for (int c = 0; c < 4; ++c) acc[r][c] += a0[r] * w0[c];
        }
        __syncthreads();
    }
#pragma unroll
    for (int r = 0; r < 4; ++r) {
        int m = bm + ty * 4 + r;
        if (m < M) {
#pragma unroll
            for (int c = 0; c < 4; ++c)
                C[(size_t)m * 256 + bj + tx * 4 + c] = acc[r][c];
        }
    }
}

// ---------- edge MLP: scores[e, i] (i = h*2+c), no atomics ----------
__global__ __launch_bounds__(256) void edge_mlp(const float* __restrict__ edge_attr,
                                                const float* __restrict__ e_w1,
                                                const float* __restrict__ e_b1,
                                                const float* __restrict__ e_w2,
                                                const float* __restrict__ e_b2,
                                                float* __restrict__ scores) {
    __shared__ float w1s[256 * 6];
    __shared__ float b1s[256];
    __shared__ float w2s[16 * 256];
    __shared__ float b2s[16];
    for (int i = threadIdx.x; i < 256 * 6; i += 256) w1s[i] = e_w1[i];
    b1s[threadIdx.x] = e_b1[threadIdx.x];
    for (int i = threadIdx.x; i < 16 * 256; i += 256) w2s[i] = e_w2[i];
    if (threadIdx.x < 16) b2s[threadIdx.x] = e_b2[threadIdx.x];
    __syncthreads();

    int e = blockIdx.x * 256 + threadIdx.x;
    if (e >= N_EDGES) return;
    float ea[6];
#pragma unroll
    for (int k = 0; k < 6; ++k) ea[k] = edge_attr[(size_t)e * 6 + k];
    float acc[16];
#pragma unroll
    for (int i = 0; i < 16; ++i) acc[i] = 0.f;
    for (int j = 0; j < 256; ++j) {
        float h = b1s[j];
#pragma unroll
        for (int k = 0; k < 6; ++k) h += ea[k] * w1s[j * 6 + k];
        h = 0.5f * h * (1.f + erff(h * 0.70710678118654752f));
#pragma unroll
        for (int i = 0; i < 16; ++i) acc[i] += h * w2s[i * 256 + j];
    }
#pragma unroll
    for (int i = 0; i < 16; ++i)
        scores[(size_t)e * 16 + i] = acc[i] + b2s[i];
}

// ---------- fused per-node segment softmax + weighted aggregation ----------
// block = node; 256 threads = 256 output dims. No atomics.
__global__ __launch_bounds__(256) void node_agg(const int* __restrict__ sorted_eid,
                                                const int* __restrict__ offs,
                                                const int* __restrict__ srcp,
                                                const float* __restrict__ scores,
                                                const float* __restrict__ V,
                                                const float* __restrict__ betap,
                                                float* __restrict__ accum,
                                                float* __restrict__ attn_out) {
    int n = blockIdx.x;
    int beg = offs[n];
    int deg = offs[n + 1] - beg;
    __shared__ float m_s[16], s_s[16];
    __shared__ float red[256];
    __shared__ float w_lds[64 * 8];
    __shared__ int eid_s[64];
    __shared__ int src_s[64];
    int tid = threadIdx.x;
    int c = tid & 15, j = tid >> 4;   // channel, slice (16 slices per channel)

    // Phase A1: per-channel max
    float mloc = -INFINITY;
    for (int k = j; k < deg; k += 16) {
        int e = sorted_eid[beg + k];
        mloc = fmaxf(mloc, scores[(size_t)e * 16 + c]);
    }
    red[tid] = mloc;
    __syncthreads();
    for (int s = 128; s >= 16; s >>= 1) {
        if (tid < s) red[tid] = fmaxf(red[tid], red[tid + s]);
        __syncthreads();
    }
    if (tid < 16) m_s[tid] = red[tid];
    __syncthreads();

    // Phase A2: per-channel sum of exp
    float m = m_s[c];
    float sloc = 0.f;
    for (int k = j; k < deg; k += 16) {
        int e = sorted_eid[beg + k];
        sloc += expf(scores[(size_t)e * 16 + c] - m);
    }
    red[tid] = sloc;
    __syncthreads();
    for (int s = 128; s >= 16; s >>= 1) {
        if (tid < s) red[tid] += red[tid + s];
        __syncthreads();
    }
    if (tid < 16) s_s[tid] = red[tid];
    __syncthreads();

    // Phase B: weights + weighted V aggregation
    float beta = *betap;
    float acc = 0.f;
    int d = tid, h = d >> 5;
    for (int base = 0; base < deg; base += 64) {
        int nchunk = min(64, deg - base);
        if (tid < nchunk) eid_s[tid] = sorted_eid[beg + base + tid];
        __syncthreads();
        if (tid < nchunk) src_s[tid] = srcp[eid_s[tid]];
        for (int p = tid; p < nchunk * 8; p += 256) {
            int k = p >> 3, hh = p & 7;
            int e = eid_s[k];
            float sc1 = scores[(size_t)e * 16 + 2 * hh];
            float sc2 = scores[(size_t)e * 16 + 2 * hh + 1];
            float w = expf(sc1 - m_s[2 * hh]) / s_s[2 * hh]
                    - beta * (expf(sc2 - m_s[2 * hh + 1]) / s_s[2 * hh + 1]);
            w_lds[k * 8 + hh] = w;
            attn_out[(size_t)e * 8 + hh] = w;
        }
        __syncthreads();
        for (int k = 0; k < nchunk; ++k) {
            acc += w_lds[k * 8 + h] * V[(size_t)src_s[k] * 256 + d];
        }
        __syncthreads();
    }
    accum[(size_t)n * 256 + d] = acc;
}

extern "C" void kernel_launch(void* const* d_in, const int* in_sizes, int n_in,
                              void* d_out, int out_size, void* d_ws, size_t ws_size,
                              hipStream_t stream) {
    const float* x         = (const float*)d_in[0];
    const float* edge_attr = (const float*)d_in[1];
    const float* v_w       = (const float*)d_in[2];
    const float* out_w     = (const float*)d_in[3];
    const float* e_w1      = (const float*)d_in[4];
    const float* e_b1      = (const float*)d_in[5];
    const float* e_w2      = (const float*)d_in[6];
    const float* e_b2      = (const float*)d_in[7];
    const float* lq        = (const float*)d_in[8];
    const float* lk        = (const float*)d_in[9];
    const int*   ei        = (const int*)d_in[10];
    const int* srcp = ei;
    const int* tgtp = ei + N_EDGES;

    float* out = (float*)d_out;                      // [N*256] out, [E*8] attn, [1] beta
    float* attn_out = out + (size_t)N_NODES * 256;
    float* beta_out = attn_out + (size_t)N_EDGES * 8;

    // workspace layout
    float* V      = (float*)d_ws;                              // 12.8M f
    float* scores = V + (size_t)N_NODES * 256;                 // 12.8M f
    float* accum  = scores + (size_t)N_EDGES * 16;             // 12.8M f
    int*   cnt    = (int*)(accum + (size_t)N_NODES * 256);     // 50K
    int*   offs   = cnt + N_NODES;                             // 50K+1
    int*   cursor = offs + N_NODES + 1;                        // 50K
    int*   partials = cursor + N_NODES;                        // 256
    int*   sorted_eid = partials + 256;                        // 800K
    float* betap  = (float*)(sorted_eid + N_EDGES);            // 1

    const int NB = (N_NODES + 255) / 256;   // 196 scan blocks

    // 1. beta
    beta_kernel<<<1, 128, 0, stream>>>(lq, lk, betap, beta_out);

    // 2. counting sort of edges by tgt
    hipMemsetAsync(cnt, 0, N_NODES * sizeof(int), stream);
    hist_kernel<<<(N_EDGES + 255) / 256, 256, 0, stream>>>(tgtp, cnt);
    scan1<<<NB, 256, 0, stream>>>(cnt, offs, partials, N_NODES);
    scan2<<<1, 256, 0, stream>>>(partials, NB);
    scan3<<<NB, 256, 0, stream>>>(offs, partials, cursor, N_NODES);
    scatter_eid<<<(N_EDGES + 255) / 256, 256, 0, stream>>>(tgtp, cursor, sorted_eid);

    // 3. V = x @ v_w.T
    gemm_nt64<<<dim3((N_NODES + 63) / 64, 4), 256, 0, stream>>>(x, v_w, V, N_NODES);

    // 4. edge MLP -> scores
    edge_mlp<<<N_EDGES / 256, 256, 0, stream>>>(edge_attr, e_w1, e_b1, e_w2, e_b2, scores);

    // 5. fused segment softmax + aggregation (dense writes, no atomics)
    node_agg<<<N_NODES, 256, 0, stream>>>(sorted_eid, offs, srcp, scores, V, betap,
                                          accum, attn_out);

    // 6. out = accum @ out_w.T
    gemm_nt64<<<dim3((N_NODES + 63) / 64, 4), 256, 0, stream>>>(accum, out_w, out, N_NODES);
}

// Round 3
// 622.395 us; speedup vs baseline: 3.0320x; 1.5647x over previous
//
#include <hip/hip_runtime.h>
#include <hip/hip_bf16.h>
#include <math.h>

#define N_NODES 50000
#define N_EDGES 800000
#define DIM 256
#define HEADS 8
#define LAMBDA_INIT 0.63212055882855767f

using bf16x8 = __attribute__((ext_vector_type(8))) short;
using f32x4  = __attribute__((ext_vector_type(4))) float;
#define MFMA16(a, b, c) __builtin_amdgcn_mfma_f32_16x16x32_bf16(a, b, c, 0, 0, 0)

__device__ __forceinline__ short f2b(float f) {
    __hip_bfloat16 h = __float2bfloat16(f);
    return *reinterpret_cast<short*>(&h);
}

// Abramowitz-Stegun 7.1.26, abs err <= 1.5e-7
__device__ __forceinline__ float fast_erf(float z) {
    float az = fabsf(z);
    float t = __builtin_amdgcn_rcpf(1.f + 0.3275911f * az);
    float p = ((((1.061405429f * t - 1.453152027f) * t + 1.421413741f) * t
                - 0.284496736f) * t + 0.254829592f) * t;
    float e = 1.f - p * __expf(-az * az);
    return copysignf(e, z);
}
__device__ __forceinline__ float gelu_f(float x) {
    return 0.5f * x * (1.f + fast_erf(0.70710678118654752f * x));
}

// ---------- beta = sigmoid(exp(dot(lq,lk)) * LAMBDA_INIT) ----------
__global__ void beta_kernel(const float* __restrict__ lq, const float* __restrict__ lk,
                            float* __restrict__ beta_ws, float* __restrict__ beta_out) {
    __shared__ float red[128];
    float v = 0.f;
    for (int i = threadIdx.x; i < 100; i += 128) v += lq[i] * lk[i];
    red[threadIdx.x] = v;
    __syncthreads();
    for (int s = 64; s > 0; s >>= 1) {
        if (threadIdx.x < s) red[threadIdx.x] += red[threadIdx.x + s];
        __syncthreads();
    }
    if (threadIdx.x == 0) {
        float l1 = expf(red[0]);
        float b = 1.f / (1.f + expf(-l1 * LAMBDA_INIT));
        *beta_ws = b;
        *beta_out = b;
    }
}

// ---------- counting sort of edges by tgt ----------
__global__ __launch_bounds__(256) void hist_kernel(const int* __restrict__ tgt,
                                                   int* __restrict__ cnt) {
    int e = blockIdx.x * 256 + threadIdx.x;
    if (e < N_EDGES) atomicAdd(&cnt[tgt[e]], 1);
}

__global__ __launch_bounds__(256) void scan1(const int* __restrict__ cnt,
                                             int* __restrict__ offs,
                                             int* __restrict__ partials, int n) {
    __shared__ int sh[256];
    int i = blockIdx.x * 256 + threadIdx.x;
    int v = (i < n) ? cnt[i] : 0;
    sh[threadIdx.x] = v;
    __syncthreads();
    for (int s = 1; s < 256; s <<= 1) {
        int add = (threadIdx.x >= s) ? sh[threadIdx.x - s] : 0;
        __syncthreads();
        sh[threadIdx.x] += add;
        __syncthreads();
    }
    if (i < n) offs[i] = sh[threadIdx.x] - v;
    if (threadIdx.x == 255) partials[blockIdx.x] = sh[255];
}

__global__ __launch_bounds__(256) void scan2(int* __restrict__ partials, int nb) {
    __shared__ int sh[256];
    int v = (threadIdx.x < nb) ? partials[threadIdx.x] : 0;
    sh[threadIdx.x] = v;
    __syncthreads();
    for (int s = 1; s < 256; s <<= 1) {
        int add = (threadIdx.x >= s) ? sh[threadIdx.x - s] : 0;
        __syncthreads();
        sh[threadIdx.x] += add;
        __syncthreads();
    }
    if (threadIdx.x < nb) partials[threadIdx.x] = sh[threadIdx.x] - v;
}

__global__ __launch_bounds__(256) void scan3(int* __restrict__ offs,
                                             const int* __restrict__ partials,
                                             int* __restrict__ cursor, int n) {
    int i = blockIdx.x * 256 + threadIdx.x;
    if (i < n) {
        int o = offs[i] + partials[blockIdx.x];
        offs[i] = o;
        cursor[i] = o;
    }
    if (i == 0) offs[n] = N_EDGES;
}

__global__ __launch_bounds__(256) void scatter_eid(const int* __restrict__ tgt,
                                                   int* __restrict__ cursor,
                                                   int* __restrict__ sorted_eid) {
    int e = blockIdx.x * 256 + threadIdx.x;
    if (e < N_EDGES) {
        int p = atomicAdd(&cursor[tgt[e]], 1);
        sorted_eid[p] = e;
    }
}

// ---------- bf16-MFMA GEMM: C[m,n] = sum_k A[m,k] * W[n,k] ----------
// A: [M][256] fp32, W: [>=bn+64][256] fp32, C: [M][256] fp32
// block tile M=128 (4 waves x 32), N=64; K chunks of 32 staged fp32->bf16 in LDS.
__global__ __launch_bounds__(256) void gemm_mfma(const float* __restrict__ A,
                                                 const float* __restrict__ W,
                                                 float* __restrict__ C, int M) {
    __shared__ __align__(16) short As[128 * 40];   // stride 40 bf16 = 80B (bank-safe)
    __shared__ __align__(16) short Ws[64 * 40];
    int tid = threadIdx.x;
    int lane = tid & 63, wv = tid >> 6;
    int l16 = lane & 15, quad = lane >> 4;
    int bm = blockIdx.x * 128, bn = blockIdx.y * 64;

    f32x4 acc[2][4];
#pragma unroll
    for (int mt = 0; mt < 2; ++mt)
#pragma unroll
        for (int nt = 0; nt < 4; ++nt) acc[mt][nt] = (f32x4){0.f, 0.f, 0.f, 0.f};

    int r = tid >> 1, hf = tid & 1;        // A staging: 2 threads/row, 16 floats each
    int rw = (tid & 127) >> 1, hw = tid & 1;  // W staging (threads 0-127)

    for (int k0 = 0; k0 < 256; k0 += 32) {
        // stage A
        {
            int m = bm + r;
            float4 f0, f1, f2, f3;
            if (m < M) {
                const float4* ap = (const float4*)&A[(size_t)m * 256 + k0 + hf * 16];
                f0 = ap[0]; f1 = ap[1]; f2 = ap[2]; f3 = ap[3];
            } else {
                f0 = f1 = f2 = f3 = make_float4(0.f, 0.f, 0.f, 0.f);
            }
            bf16x8 p0, p1;
            p0[0]=f2b(f0.x); p0[1]=f2b(f0.y); p0[2]=f2b(f0.z); p0[3]=f2b(f0.w);
            p0[4]=f2b(f1.x); p0[5]=f2b(f1.y); p0[6]=f2b(f1.z); p0[7]=f2b(f1.w);
            p1[0]=f2b(f2.x); p1[1]=f2b(f2.y); p1[2]=f2b(f2.z); p1[3]=f2b(f2.w);
            p1[4]=f2b(f3.x); p1[5]=f2b(f3.y); p1[6]=f2b(f3.z); p1[7]=f2b(f3.w);
            *(bf16x8*)&As[r * 40 + hf * 16]     = p0;
            *(bf16x8*)&As[r * 40 + hf * 16 + 8] = p1;
        }
        // stage W
        if (tid < 128) {
            const float4* wp = (const float4*)&W[(size_t)(bn + rw) * 256 + k0 + hw * 16];
            float4 f0 = wp[0], f1 = wp[1], f2 = wp[2], f3 = wp[3];
            bf16x8 p0, p1;
            p0[0]=f2b(f0.x); p0[1]=f2b(f0.y); p0[2]=f2b(f0.z); p0[3]=f2b(f0.w);
            p0[4]=f2b(f1.x); p0[5]=f2b(f1.y); p0[6]=f2b(f1.z); p0[7]=f2b(f1.w);
            p1[0]=f2b(f2.x); p1[1]=f2b(f2.y); p1[2]=f2b(f2.z); p1[3]=f2b(f2.w);
            p1[4]=f2b(f3.x); p1[5]=f2b(f3.y); p1[6]=f2b(f3.z); p1[7]=f2b(f3.w);
            *(bf16x8*)&Ws[rw * 40 + hw * 16]     = p0;
            *(bf16x8*)&Ws[rw * 40 + hw * 16 + 8] = p1;
        }
        __syncthreads();
#pragma unroll
        for (int mt = 0; mt < 2; ++mt) {
            bf16x8 afr = *(bf16x8*)&As[(wv * 32 + mt * 16 + l16) * 40 + quad * 8];
#pragma unroll
            for (int nt = 0; nt < 4; ++nt) {
                bf16x8 bfr = *(bf16x8*)&Ws[(nt * 16 + l16) * 40 + quad * 8];
                acc[mt][nt] = MFMA16(afr, bfr, acc[mt][nt]);
            }
        }
        __syncthreads();
    }
#pragma unroll
    for (int mt = 0; mt < 2; ++mt) {
#pragma unroll
        for (int rr = 0; rr < 4; ++rr) {
            int m = bm + wv * 32 + mt * 16 + quad * 4 + rr;
            if (m < M) {
#pragma unroll
                for (int nt = 0; nt < 4; ++nt)
                    C[(size_t)m * 256 + bn + nt * 16 + l16] = acc[mt][nt][rr];
            }
        }
    }
}

// ---------- edge MLP via MFMA: scores[e, i=h*2+c] ----------
// layer1: [16e x 6(pad32)] @ w1^T -> GELU -> LDS; layer2: [16e x 256] @ w2^T -> scores
__global__ __launch_bounds__(256) void edge_mlp_mfma(const float* __restrict__ edge_attr,
                                                     const float* __restrict__ e_w1,
                                                     const float* __restrict__ e_b1,
                                                     const float* __restrict__ e_w2,
                                                     const float* __restrict__ e_b2,
                                                     float* __restrict__ scores) {
    __shared__ __align__(16) short w1s[256 * 8];          // [n][k0..7] bf16, k6,7=0
    __shared__ float b1s[256];
    __shared__ __align__(16) short hbuf[4][16 * 264];     // per-wave h [m][k], stride 264

    int tid = threadIdx.x;
    {   // stage w1 + b1 (one row per thread)
        int n = tid;
#pragma unroll
        for (int k = 0; k < 6; ++k) w1s[n * 8 + k] = f2b(e_w1[n * 6 + k]);
        w1s[n * 8 + 6] = 0; w1s[n * 8 + 7] = 0;
        b1s[n] = e_b1[n];
    }
    int lane = tid & 63, wv = tid >> 6;
    int l16 = lane & 15, quad = lane >> 4;

    // w2 B-fragments in registers: lane holds w2[n=l16][k=c*32+quad*8+j]
    bf16x8 w2f[8];
#pragma unroll
    for (int c = 0; c < 8; ++c) {
        const float* p = &e_w2[l16 * 256 + c * 32 + quad * 8];
#pragma unroll
        for (int j = 0; j < 8; ++j) w2f[c][j] = f2b(p[j]);
    }
    float b2r = e_b2[l16];
    __syncthreads();

    short* h = &hbuf[wv][0];
    long eblk = (long)blockIdx.x * 256 + wv * 64;

    for (int g = 0; g < 4; ++g) {
        long e0 = eblk + g * 16;
        // layer-1 A fragment: only quad 0 carries k=0..5
        bf16x8 af = (bf16x8){0, 0, 0, 0, 0, 0, 0, 0};
        if (quad == 0) {
            const float* p = &edge_attr[(size_t)(e0 + l16) * 6];
#pragma unroll
            for (int j = 0; j < 6; ++j) af[j] = f2b(p[j]);
        }
        // 16 hidden tiles of 16
#pragma unroll 4
        for (int nt = 0; nt < 16; ++nt) {
            bf16x8 bf = (bf16x8){0, 0, 0, 0, 0, 0, 0, 0};
            if (quad == 0) bf = *(bf16x8*)&w1s[(nt * 16 + l16) * 8];
            f32x4 cc = (f32x4){0.f, 0.f, 0.f, 0.f};
            cc = MFMA16(af, bf, cc);
            float bias = b1s[nt * 16 + l16];
#pragma unroll
            for (int rr = 0; rr < 4; ++rr) {
                float hv = gelu_f(cc[rr] + bias);
                h[(quad * 4 + rr) * 264 + nt * 16 + l16] = f2b(hv);
            }
        }
        // layer 2: K=256 in 8 chunks
        f32x4 acc = (f32x4){0.f, 0.f, 0.f, 0.f};
#pragma unroll
        for (int c2 = 0; c2 < 8; ++c2) {
            bf16x8 afr = *(bf16x8*)&h[l16 * 264 + c2 * 32 + quad * 8];
            acc = MFMA16(afr, w2f[c2], acc);
        }
#pragma unroll
        for (int rr = 0; rr < 4; ++rr)
            scores[(size_t)(e0 + quad * 4 + rr) * 16 + l16] = acc[rr] + b2r;
    }
}

// ---------- fused per-node segment softmax + weighted aggregation ----------
__global__ __launch_bounds__(256) void node_agg(const int* __restrict__ sorted_eid,
                                                const int* __restrict__ offs,
                                                const int* __restrict__ srcp,
                                                const float* __restrict__ scores,
                                                const float* __restrict__ V,
                                                const float* __restrict__ betap,
                                                float* __restrict__ accum,
                                                float* __restrict__ attn_out) {
    int n = blockIdx.x;
    int beg = offs[n];
    int deg = offs[n + 1] - beg;
    __shared__ float m_s[16], s_s[16];
    __shared__ float red[256];
    __shared__ float w_lds[64 * 8];
    __shared__ int eid_s[64];
    __shared__ int src_s[64];
    int tid = threadIdx.x;
    int c = tid & 15, j = tid >> 4;

    float mloc = -INFINITY;
    for (int k = j; k < deg; k += 16) {
        int e = sorted_eid[beg + k];
        mloc = fmaxf(mloc, scores[(size_t)e * 16 + c]);
    }
    red[tid] = mloc;
    __syncthreads();
    for (int s = 128; s >= 16; s >>= 1) {
        if (tid < s) red[tid] = fmaxf(red[tid], red[tid + s]);
        __syncthreads();
    }
    if (tid < 16) m_s[tid] = red[tid];
    __syncthreads();

    float m = m_s[c];
    float sloc = 0.f;
    for (int k = j; k < deg; k += 16) {
        int e = sorted_eid[beg + k];
        sloc += expf(scores[(size_t)e * 16 + c] - m);
    }
    red[tid] = sloc;
    __syncthreads();
    for (int s = 128; s >= 16; s >>= 1) {
        if (tid < s) red[tid] += red[tid + s];
        __syncthreads();
    }
    if (tid < 16) s_s[tid] = red[tid];
    __syncthreads();

    float beta = *betap;
    float acc = 0.f;
    int d = tid, h = d >> 5;
    for (int base = 0; base < deg; base += 64) {
        int nchunk = min(64, deg - base);
        if (tid < nchunk) eid_s[tid] = sorted_eid[beg + base + tid];
        __syncthreads();
        if (tid < nchunk) src_s[tid] = srcp[eid_s[tid]];
        for (int p = tid; p < nchunk * 8; p += 256) {
            int k = p >> 3, hh = p & 7;
            int e = eid_s[k];
            float sc1 = scores[(size_t)e * 16 + 2 * hh];
            float sc2 = scores[(size_t)e * 16 + 2 * hh + 1];
            float w = expf(sc1 - m_s[2 * hh]) / s_s[2 * hh]
                    - beta * (expf(sc2 - m_s[2 * hh + 1]) / s_s[2 * hh + 1]);
            w_lds[k * 8 + hh] = w;
            attn_out[(size_t)e * 8 + hh] = w;
        }
        __syncthreads();
        for (int k = 0; k < nchunk; ++k) {
            acc += w_lds[k * 8 + h] * V[(size_t)src_s[k] * 256 + d];
        }
        __syncthreads();
    }
    accum[(size_t)n * 256 + d] = acc;
}

extern "C" void kernel_launch(void* const* d_in, const int* in_sizes, int n_in,
                              void* d_out, int out_size, void* d_ws, size_t ws_size,
                              hipStream_t stream) {
    const float* x         = (const float*)d_in[0];
    const float* edge_attr = (const float*)d_in[1];
    const float* v_w       = (const float*)d_in[2];
    const float* out_w     = (const float*)d_in[3];
    const float* e_w1      = (const float*)d_in[4];
    const float* e_b1      = (const float*)d_in[5];
    const float* e_w2      = (const float*)d_in[6];
    const float* e_b2      = (const float*)d_in[7];
    const float* lq        = (const float*)d_in[8];
    const float* lk        = (const float*)d_in[9];
    const int*   ei        = (const int*)d_in[10];
    const int* srcp = ei;
    const int* tgtp = ei + N_EDGES;

    float* out = (float*)d_out;
    float* attn_out = out + (size_t)N_NODES * 256;
    float* beta_out = attn_out + (size_t)N_EDGES * 8;

    float* V      = (float*)d_ws;
    float* scores = V + (size_t)N_NODES * 256;
    float* accum  = scores + (size_t)N_EDGES * 16;
    int*   cnt    = (int*)(accum + (size_t)N_NODES * 256);
    int*   offs   = cnt + N_NODES;
    int*   cursor = offs + N_NODES + 1;
    int*   partials = cursor + N_NODES;
    int*   sorted_eid = partials + 256;
    float* betap  = (float*)(sorted_eid + N_EDGES);

    const int NB = (N_NODES + 255) / 256;

    beta_kernel<<<1, 128, 0, stream>>>(lq, lk, betap, beta_out);

    hipMemsetAsync(cnt, 0, N_NODES * sizeof(int), stream);
    hist_kernel<<<(N_EDGES + 255) / 256, 256, 0, stream>>>(tgtp, cnt);
    scan1<<<NB, 256, 0, stream>>>(cnt, offs, partials, N_NODES);
    scan2<<<1, 256, 0, stream>>>(partials, NB);
    scan3<<<NB, 256, 0, stream>>>(offs, partials, cursor, N_NODES);
    scatter_eid<<<(N_EDGES + 255) / 256, 256, 0, stream>>>(tgtp, cursor, sorted_eid);

    // V = x @ v_w.T  (bf16 MFMA)
    gemm_mfma<<<dim3((N_NODES + 127) / 128, 4), 256, 0, stream>>>(x, v_w, V, N_NODES);

    // edge MLP -> scores (MFMA both layers)
    edge_mlp_mfma<<<N_EDGES / 256, 256, 0, stream>>>(edge_attr, e_w1, e_b1, e_w2, e_b2,
                                                     scores);

    node_agg<<<N_NODES, 256, 0, stream>>>(sorted_eid, offs, srcp, scores, V, betap,
                                          accum, attn_out);

    // out = accum @ out_w.T  (bf16 MFMA)
    gemm_mfma<<<dim3((N_NODES + 127) / 128, 4), 256, 0, stream>>>(accum, out_w, out, N_NODES);
}

// Round 5
// 594.680 us; speedup vs baseline: 3.1734x; 1.0466x over previous
//
#include <hip/hip_runtime.h>
#include <hip/hip_bf16.h>
#include <math.h>

#define N_NODES 50000
#define N_EDGES 800000
#define DIM 256
#define HEADS 8
#define LAMBDA_INIT 0.63212055882855767f

using bf16x8 = __attribute__((ext_vector_type(8))) short;
using bf16x4 = __attribute__((ext_vector_type(4))) short;
using f32x4  = __attribute__((ext_vector_type(4))) float;
#define MFMA16(a, b, c) __builtin_amdgcn_mfma_f32_16x16x32_bf16(a, b, c, 0, 0, 0)

__device__ __forceinline__ short f2b(float f) {
    __hip_bfloat16 h = __float2bfloat16(f);
    return *reinterpret_cast<short*>(&h);
}
__device__ __forceinline__ float b2f(short s) {
    unsigned u = ((unsigned)(unsigned short)s) << 16;
    return __uint_as_float(u);
}

// Abramowitz-Stegun 7.1.26, abs err <= 1.5e-7
__device__ __forceinline__ float fast_erf(float z) {
    float az = fabsf(z);
    float t = __builtin_amdgcn_rcpf(1.f + 0.3275911f * az);
    float p = ((((1.061405429f * t - 1.453152027f) * t + 1.421413741f) * t
                - 0.284496736f) * t + 0.254829592f) * t;
    float e = 1.f - p * __expf(-az * az);
    return copysignf(e, z);
}
__device__ __forceinline__ float gelu_f(float x) {
    return 0.5f * x * (1.f + fast_erf(0.70710678118654752f * x));
}

// ---------- beta ----------
__global__ void beta_kernel(const float* __restrict__ lq, const float* __restrict__ lk,
                            float* __restrict__ beta_ws, float* __restrict__ beta_out) {
    __shared__ float red[128];
    float v = 0.f;
    for (int i = threadIdx.x; i < 100; i += 128) v += lq[i] * lk[i];
    red[threadIdx.x] = v;
    __syncthreads();
    for (int s = 64; s > 0; s >>= 1) {
        if (threadIdx.x < s) red[threadIdx.x] += red[threadIdx.x + s];
        __syncthreads();
    }
    if (threadIdx.x == 0) {
        float l1 = expf(red[0]);
        float b = 1.f / (1.f + expf(-l1 * LAMBDA_INIT));
        *beta_ws = b;
        *beta_out = b;
    }
}

// ---------- counting sort of edges by tgt ----------
__global__ __launch_bounds__(256) void hist_kernel(const int* __restrict__ tgt,
                                                   int* __restrict__ cnt) {
    int e = blockIdx.x * 256 + threadIdx.x;
    if (e < N_EDGES) atomicAdd(&cnt[tgt[e]], 1);
}

__global__ __launch_bounds__(256) void scan1(const int* __restrict__ cnt,
                                             int* __restrict__ offs,
                                             int* __restrict__ partials, int n) {
    __shared__ int sh[256];
    int i = blockIdx.x * 256 + threadIdx.x;
    int v = (i < n) ? cnt[i] : 0;
    sh[threadIdx.x] = v;
    __syncthreads();
    for (int s = 1; s < 256; s <<= 1) {
        int add = (threadIdx.x >= s) ? sh[threadIdx.x - s] : 0;
        __syncthreads();
        sh[threadIdx.x] += add;
        __syncthreads();
    }
    if (i < n) offs[i] = sh[threadIdx.x] - v;
    if (threadIdx.x == 255) partials[blockIdx.x] = sh[255];
}

__global__ __launch_bounds__(256) void scan2(int* __restrict__ partials, int nb) {
    __shared__ int sh[256];
    int v = (threadIdx.x < nb) ? partials[threadIdx.x] : 0;
    sh[threadIdx.x] = v;
    __syncthreads();
    for (int s = 1; s < 256; s <<= 1) {
        int add = (threadIdx.x >= s) ? sh[threadIdx.x - s] : 0;
        __syncthreads();
        sh[threadIdx.x] += add;
        __syncthreads();
    }
    if (threadIdx.x < nb) partials[threadIdx.x] = sh[threadIdx.x] - v;
}

__global__ __launch_bounds__(256) void scan3(int* __restrict__ offs,
                                             const int* __restrict__ partials,
                                             int* __restrict__ cursor, int n) {
    int i = blockIdx.x * 256 + threadIdx.x;
    if (i < n) {
        int o = offs[i] + partials[blockIdx.x];
        offs[i] = o;
        cursor[i] = o;
    }
    if (i == 0) offs[n] = N_EDGES;
}

__global__ __launch_bounds__(256) void scatter_eid(const int* __restrict__ tgt,
                                                   int* __restrict__ cursor,
                                                   int* __restrict__ sorted_eid) {
    int e = blockIdx.x * 256 + threadIdx.x;
    if (e < N_EDGES) {
        int p = atomicAdd(&cursor[tgt[e]], 1);
        sorted_eid[p] = e;
    }
}

// ---------- bf16-MFMA GEMM: C[m,n] = sum_k A[m,k] * W[n,k] ----------
// ABF: A is bf16 [M][256], else fp32. CBF: C is bf16, else fp32.
template <bool ABF, bool CBF>
__global__ __launch_bounds__(256) void gemm_mfma_t(const void* __restrict__ Av,
                                                   const float* __restrict__ W,
                                                   void* __restrict__ Cv, int M) {
    __shared__ __align__(16) short As[128 * 40];
    __shared__ __align__(16) short Ws[64 * 40];
    int tid = threadIdx.x;
    int lane = tid & 63, wv = tid >> 6;
    int l16 = lane & 15, quad = lane >> 4;
    int bm = blockIdx.x * 128, bn = blockIdx.y * 64;

    f32x4 acc[2][4];
#pragma unroll
    for (int mt = 0; mt < 2; ++mt)
#pragma unroll
        for (int nt = 0; nt < 4; ++nt) acc[mt][nt] = (f32x4){0.f, 0.f, 0.f, 0.f};

    int r = tid >> 1, hf = tid & 1;
    int rw = (tid & 127) >> 1, hw = tid & 1;

    for (int k0 = 0; k0 < 256; k0 += 32) {
        // stage A
        {
            int m = bm + r;
            bf16x8 p0, p1;
            if (ABF) {
                if (m < M) {
                    const bf16x8* ap =
                        (const bf16x8*)&((const short*)Av)[(size_t)m * 256 + k0 + hf * 16];
                    p0 = ap[0]; p1 = ap[1];
                } else {
                    p0 = (bf16x8){0,0,0,0,0,0,0,0}; p1 = p0;
                }
            } else {
                float4 f0, f1, f2, f3;
                if (m < M) {
                    const float4* ap =
                        (const float4*)&((const float*)Av)[(size_t)m * 256 + k0 + hf * 16];
                    f0 = ap[0]; f1 = ap[1]; f2 = ap[2]; f3 = ap[3];
                } else {
                    f0 = f1 = f2 = f3 = make_float4(0.f, 0.f, 0.f, 0.f);
                }
                p0[0]=f2b(f0.x); p0[1]=f2b(f0.y); p0[2]=f2b(f0.z); p0[3]=f2b(f0.w);
                p0[4]=f2b(f1.x); p0[5]=f2b(f1.y); p0[6]=f2b(f1.z); p0[7]=f2b(f1.w);
                p1[0]=f2b(f2.x); p1[1]=f2b(f2.y); p1[2]=f2b(f2.z); p1[3]=f2b(f2.w);
                p1[4]=f2b(f3.x); p1[5]=f2b(f3.y); p1[6]=f2b(f3.z); p1[7]=f2b(f3.w);
            }
            *(bf16x8*)&As[r * 40 + hf * 16]     = p0;
            *(bf16x8*)&As[r * 40 + hf * 16 + 8] = p1;
        }
        // stage W (fp32)
        if (tid < 128) {
            const float4* wp = (const float4*)&W[(size_t)(bn + rw) * 256 + k0 + hw * 16];
            float4 f0 = wp[0], f1 = wp[1], f2 = wp[2], f3 = wp[3];
            bf16x8 p0, p1;
            p0[0]=f2b(f0.x); p0[1]=f2b(f0.y); p0[2]=f2b(f0.z); p0[3]=f2b(f0.w);
            p0[4]=f2b(f1.x); p0[5]=f2b(f1.y); p0[6]=f2b(f1.z); p0[7]=f2b(f1.w);
            p1[0]=f2b(f2.x); p1[1]=f2b(f2.y); p1[2]=f2b(f2.z); p1[3]=f2b(f2.w);
            p1[4]=f2b(f3.x); p1[5]=f2b(f3.y); p1[6]=f2b(f3.z); p1[7]=f2b(f3.w);
            *(bf16x8*)&Ws[rw * 40 + hw * 16]     = p0;
            *(bf16x8*)&Ws[rw * 40 + hw * 16 + 8] = p1;
        }
        __syncthreads();
#pragma unroll
        for (int mt = 0; mt < 2; ++mt) {
            bf16x8 afr = *(bf16x8*)&As[(wv * 32 + mt * 16 + l16) * 40 + quad * 8];
#pragma unroll
            for (int nt = 0; nt < 4; ++nt) {
                bf16x8 bfr = *(bf16x8*)&Ws[(nt * 16 + l16) * 40 + quad * 8];
                acc[mt][nt] = MFMA16(afr, bfr, acc[mt][nt]);
            }
        }
        __syncthreads();
    }
#pragma unroll
    for (int mt = 0; mt < 2; ++mt) {
#pragma unroll
        for (int rr = 0; rr < 4; ++rr) {
            int m = bm + wv * 32 + mt * 16 + quad * 4 + rr;
            if (m < M) {
#pragma unroll
                for (int nt = 0; nt < 4; ++nt) {
                    if (CBF)
                        ((short*)Cv)[(size_t)m * 256 + bn + nt * 16 + l16] =
                            f2b(acc[mt][nt][rr]);
                    else
                        ((float*)Cv)[(size_t)m * 256 + bn + nt * 16 + l16] =
                            acc[mt][nt][rr];
                }
            }
        }
    }
}

// ---------- edge MLP via MFMA ----------
__global__ __launch_bounds__(256) void edge_mlp_mfma(const float* __restrict__ edge_attr,
                                                     const float* __restrict__ e_w1,
                                                     const float* __restrict__ e_b1,
                                                     const float* __restrict__ e_w2,
                                                     const float* __restrict__ e_b2,
                                                     float* __restrict__ scores) {
    __shared__ __align__(16) short w1s[256 * 8];
    __shared__ float b1s[256];
    __shared__ __align__(16) short hbuf[4][16 * 264];

    int tid = threadIdx.x;
    {
        int n = tid;
#pragma unroll
        for (int k = 0; k < 6; ++k) w1s[n * 8 + k] = f2b(e_w1[n * 6 + k]);
        w1s[n * 8 + 6] = 0; w1s[n * 8 + 7] = 0;
        b1s[n] = e_b1[n];
    }
    int lane = tid & 63, wv = tid >> 6;
    int l16 = lane & 15, quad = lane >> 4;

    bf16x8 w2f[8];
#pragma unroll
    for (int c = 0; c < 8; ++c) {
        const float* p = &e_w2[l16 * 256 + c * 32 + quad * 8];
#pragma unroll
        for (int j = 0; j < 8; ++j) w2f[c][j] = f2b(p[j]);
    }
    float b2r = e_b2[l16];
    __syncthreads();

    short* h = &hbuf[wv][0];
    long eblk = (long)blockIdx.x * 256 + wv * 64;

    for (int g = 0; g < 4; ++g) {
        long e0 = eblk + g * 16;
        bf16x8 af = (bf16x8){0, 0, 0, 0, 0, 0, 0, 0};
        if (quad == 0) {
            const float* p = &edge_attr[(size_t)(e0 + l16) * 6];
#pragma unroll
            for (int j = 0; j < 6; ++j) af[j] = f2b(p[j]);
        }
#pragma unroll 4
        for (int nt = 0; nt < 16; ++nt) {
            bf16x8 bf = (bf16x8){0, 0, 0, 0, 0, 0, 0, 0};
            if (quad == 0) bf = *(bf16x8*)&w1s[(nt * 16 + l16) * 8];
            f32x4 cc = (f32x4){0.f, 0.f, 0.f, 0.f};
            cc = MFMA16(af, bf, cc);
            float bias = b1s[nt * 16 + l16];
#pragma unroll
            for (int rr = 0; rr < 4; ++rr) {
                float hv = gelu_f(cc[rr] + bias);
                h[(quad * 4 + rr) * 264 + nt * 16 + l16] = f2b(hv);
            }
        }
        f32x4 acc = (f32x4){0.f, 0.f, 0.f, 0.f};
#pragma unroll
        for (int c2 = 0; c2 < 8; ++c2) {
            bf16x8 afr = *(bf16x8*)&h[l16 * 264 + c2 * 32 + quad * 8];
            acc = MFMA16(afr, w2f[c2], acc);
        }
#pragma unroll
        for (int rr = 0; rr < 4; ++rr)
            scores[(size_t)(e0 + quad * 4 + rr) * 16 + l16] = acc[rr] + b2r;
    }
}

// ---------- fused per-node segment softmax + weighted aggregation ----------
// block = node; 256 threads = 256 output dims. Verified structure (R3), bf16 V/accum.
__global__ __launch_bounds__(256) void node_agg(const int* __restrict__ sorted_eid,
                                                const int* __restrict__ offs,
                                                const int* __restrict__ srcp,
                                                const float* __restrict__ scores,
                                                const short* __restrict__ Vb,
                                                const float* __restrict__ betap,
                                                short* __restrict__ accumb,
                                                float* __restrict__ attn_out) {
    int n = blockIdx.x;
    int beg = offs[n];
    int deg = offs[n + 1] - beg;
    __shared__ float m_s[16], s_s[16];
    __shared__ float red[256];
    __shared__ float w_lds[64 * 8];
    __shared__ int eid_s[64];
    __shared__ int src_s[64];
    int tid = threadIdx.x;
    int c = tid & 15, j = tid >> 4;

    float mloc = -INFINITY;
    for (int k = j; k < deg; k += 16) {
        int e = sorted_eid[beg + k];
        mloc = fmaxf(mloc, scores[(size_t)e * 16 + c]);
    }
    red[tid] = mloc;
    __syncthreads();
    for (int s = 128; s >= 16; s >>= 1) {
        if (tid < s) red[tid] = fmaxf(red[tid], red[tid + s]);
        __syncthreads();
    }
    if (tid < 16) m_s[tid] = red[tid];
    __syncthreads();

    float m = m_s[c];
    float sloc = 0.f;
    for (int k = j; k < deg; k += 16) {
        int e = sorted_eid[beg + k];
        sloc += expf(scores[(size_t)e * 16 + c] - m);
    }
    red[tid] = sloc;
    __syncthreads();
    for (int s = 128; s >= 16; s >>= 1) {
        if (tid < s) red[tid] += red[tid + s];
        __syncthreads();
    }
    if (tid < 16) s_s[tid] = red[tid];
    __syncthreads();

    float beta = *betap;
    float acc = 0.f;
    int d = tid, h = d >> 5;
    for (int base = 0; base < deg; base += 64) {
        int nchunk = min(64, deg - base);
        if (tid < nchunk) eid_s[tid] = sorted_eid[beg + base + tid];
        __syncthreads();
        if (tid < nchunk) src_s[tid] = srcp[eid_s[tid]];
        for (int p = tid; p < nchunk * 8; p += 256) {
            int k = p >> 3, hh = p & 7;
            int e = eid_s[k];
            float sc1 = scores[(size_t)e * 16 + 2 * hh];
            float sc2 = scores[(size_t)e * 16 + 2 * hh + 1];
            float w = expf(sc1 - m_s[2 * hh]) / s_s[2 * hh]
                    - beta * (expf(sc2 - m_s[2 * hh + 1]) / s_s[2 * hh + 1]);
            w_lds[k * 8 + hh] = w;
            attn_out[(size_t)e * 8 + hh] = w;
        }
        __syncthreads();
        for (int k = 0; k < nchunk; ++k) {
            acc += w_lds[k * 8 + h] * b2f(Vb[(size_t)src_s[k] * 256 + d]);
        }
        __syncthreads();
    }
    accumb[(size_t)n * 256 + d] = f2b(acc);
}

extern "C" void kernel_launch(void* const* d_in, const int* in_sizes, int n_in,
                              void* d_out, int out_size, void* d_ws, size_t ws_size,
                              hipStream_t stream) {
    const float* x         = (const float*)d_in[0];
    const float* edge_attr = (const float*)d_in[1];
    const float* v_w       = (const float*)d_in[2];
    const float* out_w     = (const float*)d_in[3];
    const float* e_w1      = (const float*)d_in[4];
    const float* e_b1      = (const float*)d_in[5];
    const float* e_w2      = (const float*)d_in[6];
    const float* e_b2      = (const float*)d_in[7];
    const float* lq        = (const float*)d_in[8];
    const float* lk        = (const float*)d_in[9];
    const int*   ei        = (const int*)d_in[10];
    const int* srcp = ei;
    const int* tgtp = ei + N_EDGES;

    float* out = (float*)d_out;
    float* attn_out = out + (size_t)N_NODES * 256;
    float* beta_out = attn_out + (size_t)N_EDGES * 8;

    // workspace layout
    short* Vb     = (short*)d_ws;                              // N*256 bf16
    float* scores = (float*)(Vb + (size_t)N_NODES * 256);      // E*16 f32
    short* accumb = (short*)(scores + (size_t)N_EDGES * 16);   // N*256 bf16
    int*   cnt    = (int*)(accumb + (size_t)N_NODES * 256);
    int*   offs   = cnt + N_NODES;
    int*   cursor = offs + N_NODES + 1;
    int*   partials = cursor + N_NODES;
    int*   sorted_eid = partials + 256;
    float* betap  = (float*)(sorted_eid + N_EDGES);

    const int NB = (N_NODES + 255) / 256;

    beta_kernel<<<1, 128, 0, stream>>>(lq, lk, betap, beta_out);

    hipMemsetAsync(cnt, 0, N_NODES * sizeof(int), stream);
    hist_kernel<<<(N_EDGES + 255) / 256, 256, 0, stream>>>(tgtp, cnt);
    scan1<<<NB, 256, 0, stream>>>(cnt, offs, partials, N_NODES);
    scan2<<<1, 256, 0, stream>>>(partials, NB);
    scan3<<<NB, 256, 0, stream>>>(offs, partials, cursor, N_NODES);
    scatter_eid<<<(N_EDGES + 255) / 256, 256, 0, stream>>>(tgtp, cursor, sorted_eid);

    // V(bf16) = x @ v_w.T
    gemm_mfma_t<false, true><<<dim3((N_NODES + 127) / 128, 4), 256, 0, stream>>>(
        x, v_w, Vb, N_NODES);

    // edge MLP -> scores
    edge_mlp_mfma<<<N_EDGES / 256, 256, 0, stream>>>(edge_attr, e_w1, e_b1, e_w2, e_b2,
                                                     scores);

    // fused softmax + aggregation (verified block-per-node structure)
    node_agg<<<N_NODES, 256, 0, stream>>>(sorted_eid, offs, srcp, scores, Vb, betap,
                                          accumb, attn_out);

    // out = accum(bf16) @ out_w.T
    gemm_mfma_t<true, false><<<dim3((N_NODES + 127) / 128, 4), 256, 0, stream>>>(
        accumb, out_w, out, N_NODES);
}

// Round 6
// 559.979 us; speedup vs baseline: 3.3700x; 1.0620x over previous
//
#include <hip/hip_runtime.h>
#include <hip/hip_bf16.h>
#include <math.h>

#define N_NODES 50000
#define N_EDGES 800000
#define DIM 256
#define HEADS 8
#define LAMBDA_INIT 0.63212055882855767f

using bf16x8 = __attribute__((ext_vector_type(8))) short;
using bf16x4 = __attribute__((ext_vector_type(4))) short;
using f32x4  = __attribute__((ext_vector_type(4))) float;
#define MFMA16(a, b, c) __builtin_amdgcn_mfma_f32_16x16x32_bf16(a, b, c, 0, 0, 0)

__device__ __forceinline__ short f2b(float f) {
    __hip_bfloat16 h = __float2bfloat16(f);
    return *reinterpret_cast<short*>(&h);
}
__device__ __forceinline__ float b2f(short s) {
    unsigned u = ((unsigned)(unsigned short)s) << 16;
    return __uint_as_float(u);
}

// Abramowitz-Stegun 7.1.26, abs err <= 1.5e-7
__device__ __forceinline__ float fast_erf(float z) {
    float az = fabsf(z);
    float t = __builtin_amdgcn_rcpf(1.f + 0.3275911f * az);
    float p = ((((1.061405429f * t - 1.453152027f) * t + 1.421413741f) * t
                - 0.284496736f) * t + 0.254829592f) * t;
    float e = 1.f - p * __expf(-az * az);
    return copysignf(e, z);
}
__device__ __forceinline__ float gelu_f(float x) {
    return 0.5f * x * (1.f + fast_erf(0.70710678118654752f * x));
}

// ---------- beta ----------
__global__ void beta_kernel(const float* __restrict__ lq, const float* __restrict__ lk,
                            float* __restrict__ beta_ws, float* __restrict__ beta_out) {
    __shared__ float red[128];
    float v = 0.f;
    for (int i = threadIdx.x; i < 100; i += 128) v += lq[i] * lk[i];
    red[threadIdx.x] = v;
    __syncthreads();
    for (int s = 64; s > 0; s >>= 1) {
        if (threadIdx.x < s) red[threadIdx.x] += red[threadIdx.x + s];
        __syncthreads();
    }
    if (threadIdx.x == 0) {
        float l1 = expf(red[0]);
        float b = 1.f / (1.f + expf(-l1 * LAMBDA_INIT));
        *beta_ws = b;
        *beta_out = b;
    }
}

// ---------- counting sort of edges by tgt ----------
__global__ __launch_bounds__(256) void hist_kernel(const int* __restrict__ tgt,
                                                   int* __restrict__ cnt) {
    int e = blockIdx.x * 256 + threadIdx.x;
    if (e < N_EDGES) atomicAdd(&cnt[tgt[e]], 1);
}

__global__ __launch_bounds__(256) void scan1(const int* __restrict__ cnt,
                                             int* __restrict__ offs,
                                             int* __restrict__ partials, int n) {
    __shared__ int sh[256];
    int i = blockIdx.x * 256 + threadIdx.x;
    int v = (i < n) ? cnt[i] : 0;
    sh[threadIdx.x] = v;
    __syncthreads();
    for (int s = 1; s < 256; s <<= 1) {
        int add = (threadIdx.x >= s) ? sh[threadIdx.x - s] : 0;
        __syncthreads();
        sh[threadIdx.x] += add;
        __syncthreads();
    }
    if (i < n) offs[i] = sh[threadIdx.x] - v;
    if (threadIdx.x == 255) partials[blockIdx.x] = sh[255];
}

__global__ __launch_bounds__(256) void scan2(int* __restrict__ partials, int nb) {
    __shared__ int sh[256];
    int v = (threadIdx.x < nb) ? partials[threadIdx.x] : 0;
    sh[threadIdx.x] = v;
    __syncthreads();
    for (int s = 1; s < 256; s <<= 1) {
        int add = (threadIdx.x >= s) ? sh[threadIdx.x - s] : 0;
        __syncthreads();
        sh[threadIdx.x] += add;
        __syncthreads();
    }
    if (threadIdx.x < nb) partials[threadIdx.x] = sh[threadIdx.x] - v;
}

__global__ __launch_bounds__(256) void scan3(int* __restrict__ offs,
                                             const int* __restrict__ partials,
                                             int* __restrict__ cursor, int n) {
    int i = blockIdx.x * 256 + threadIdx.x;
    if (i < n) {
        int o = offs[i] + partials[blockIdx.x];
        offs[i] = o;
        cursor[i] = o;
    }
    if (i == 0) offs[n] = N_EDGES;
}

__global__ __launch_bounds__(256) void scatter_eid(const int* __restrict__ tgt,
                                                   int* __restrict__ cursor,
                                                   int* __restrict__ sorted_eid) {
    int e = blockIdx.x * 256 + threadIdx.x;
    if (e < N_EDGES) {
        int p = atomicAdd(&cursor[tgt[e]], 1);
        sorted_eid[p] = e;
    }
}

// ---------- bf16-MFMA GEMM: C[m,n] = sum_k A[m,k] * W[n,k] ----------
template <bool ABF, bool CBF>
__global__ __launch_bounds__(256) void gemm_mfma_t(const void* __restrict__ Av,
                                                   const float* __restrict__ W,
                                                   void* __restrict__ Cv, int M) {
    __shared__ __align__(16) short As[128 * 40];
    __shared__ __align__(16) short Ws[64 * 40];
    int tid = threadIdx.x;
    int lane = tid & 63, wv = tid >> 6;
    int l16 = lane & 15, quad = lane >> 4;
    int bm = blockIdx.x * 128, bn = blockIdx.y * 64;

    f32x4 acc[2][4];
#pragma unroll
    for (int mt = 0; mt < 2; ++mt)
#pragma unroll
        for (int nt = 0; nt < 4; ++nt) acc[mt][nt] = (f32x4){0.f, 0.f, 0.f, 0.f};

    int r = tid >> 1, hf = tid & 1;
    int rw = (tid & 127) >> 1, hw = tid & 1;

    for (int k0 = 0; k0 < 256; k0 += 32) {
        {
            int m = bm + r;
            bf16x8 p0, p1;
            if (ABF) {
                if (m < M) {
                    const bf16x8* ap =
                        (const bf16x8*)&((const short*)Av)[(size_t)m * 256 + k0 + hf * 16];
                    p0 = ap[0]; p1 = ap[1];
                } else {
                    p0 = (bf16x8){0,0,0,0,0,0,0,0}; p1 = p0;
                }
            } else {
                float4 f0, f1, f2, f3;
                if (m < M) {
                    const float4* ap =
                        (const float4*)&((const float*)Av)[(size_t)m * 256 + k0 + hf * 16];
                    f0 = ap[0]; f1 = ap[1]; f2 = ap[2]; f3 = ap[3];
                } else {
                    f0 = f1 = f2 = f3 = make_float4(0.f, 0.f, 0.f, 0.f);
                }
                p0[0]=f2b(f0.x); p0[1]=f2b(f0.y); p0[2]=f2b(f0.z); p0[3]=f2b(f0.w);
                p0[4]=f2b(f1.x); p0[5]=f2b(f1.y); p0[6]=f2b(f1.z); p0[7]=f2b(f1.w);
                p1[0]=f2b(f2.x); p1[1]=f2b(f2.y); p1[2]=f2b(f2.z); p1[3]=f2b(f2.w);
                p1[4]=f2b(f3.x); p1[5]=f2b(f3.y); p1[6]=f2b(f3.z); p1[7]=f2b(f3.w);
            }
            *(bf16x8*)&As[r * 40 + hf * 16]     = p0;
            *(bf16x8*)&As[r * 40 + hf * 16 + 8] = p1;
        }
        if (tid < 128) {
            const float4* wp = (const float4*)&W[(size_t)(bn + rw) * 256 + k0 + hw * 16];
            float4 f0 = wp[0], f1 = wp[1], f2 = wp[2], f3 = wp[3];
            bf16x8 p0, p1;
            p0[0]=f2b(f0.x); p0[1]=f2b(f0.y); p0[2]=f2b(f0.z); p0[3]=f2b(f0.w);
            p0[4]=f2b(f1.x); p0[5]=f2b(f1.y); p0[6]=f2b(f1.z); p0[7]=f2b(f1.w);
            p1[0]=f2b(f2.x); p1[1]=f2b(f2.y); p1[2]=f2b(f2.z); p1[3]=f2b(f2.w);
            p1[4]=f2b(f3.x); p1[5]=f2b(f3.y); p1[6]=f2b(f3.z); p1[7]=f2b(f3.w);
            *(bf16x8*)&Ws[rw * 40 + hw * 16]     = p0;
            *(bf16x8*)&Ws[rw * 40 + hw * 16 + 8] = p1;
        }
        __syncthreads();
#pragma unroll
        for (int mt = 0; mt < 2; ++mt) {
            bf16x8 afr = *(bf16x8*)&As[(wv * 32 + mt * 16 + l16) * 40 + quad * 8];
#pragma unroll
            for (int nt = 0; nt < 4; ++nt) {
                bf16x8 bfr = *(bf16x8*)&Ws[(nt * 16 + l16) * 40 + quad * 8];
                acc[mt][nt] = MFMA16(afr, bfr, acc[mt][nt]);
            }
        }
        __syncthreads();
    }
#pragma unroll
    for (int mt = 0; mt < 2; ++mt) {
#pragma unroll
        for (int rr = 0; rr < 4; ++rr) {
            int m = bm + wv * 32 + mt * 16 + quad * 4 + rr;
            if (m < M) {
#pragma unroll
                for (int nt = 0; nt < 4; ++nt) {
                    if (CBF)
                        ((short*)Cv)[(size_t)m * 256 + bn + nt * 16 + l16] =
                            f2b(acc[mt][nt][rr]);
                    else
                        ((float*)Cv)[(size_t)m * 256 + bn + nt * 16 + l16] =
                            acc[mt][nt][rr];
                }
            }
        }
    }
}

// ---------- edge MLP via MFMA ----------
__global__ __launch_bounds__(256) void edge_mlp_mfma(const float* __restrict__ edge_attr,
                                                     const float* __restrict__ e_w1,
                                                     const float* __restrict__ e_b1,
                                                     const float* __restrict__ e_w2,
                                                     const float* __restrict__ e_b2,
                                                     float* __restrict__ scores) {
    __shared__ __align__(16) short w1s[256 * 8];
    __shared__ float b1s[256];
    __shared__ __align__(16) short hbuf[4][16 * 264];

    int tid = threadIdx.x;
    {
        int n = tid;
#pragma unroll
        for (int k = 0; k < 6; ++k) w1s[n * 8 + k] = f2b(e_w1[n * 6 + k]);
        w1s[n * 8 + 6] = 0; w1s[n * 8 + 7] = 0;
        b1s[n] = e_b1[n];
    }
    int lane = tid & 63, wv = tid >> 6;
    int l16 = lane & 15, quad = lane >> 4;

    bf16x8 w2f[8];
#pragma unroll
    for (int c = 0; c < 8; ++c) {
        const float* p = &e_w2[l16 * 256 + c * 32 + quad * 8];
#pragma unroll
        for (int j = 0; j < 8; ++j) w2f[c][j] = f2b(p[j]);
    }
    float b2r = e_b2[l16];
    __syncthreads();

    short* h = &hbuf[wv][0];
    long eblk = (long)blockIdx.x * 256 + wv * 64;

    for (int g = 0; g < 4; ++g) {
        long e0 = eblk + g * 16;
        bf16x8 af = (bf16x8){0, 0, 0, 0, 0, 0, 0, 0};
        if (quad == 0) {
            const float* p = &edge_attr[(size_t)(e0 + l16) * 6];
#pragma unroll
            for (int j = 0; j < 6; ++j) af[j] = f2b(p[j]);
        }
#pragma unroll 4
        for (int nt = 0; nt < 16; ++nt) {
            bf16x8 bf = (bf16x8){0, 0, 0, 0, 0, 0, 0, 0};
            if (quad == 0) bf = *(bf16x8*)&w1s[(nt * 16 + l16) * 8];
            f32x4 cc = (f32x4){0.f, 0.f, 0.f, 0.f};
            cc = MFMA16(af, bf, cc);
            float bias = b1s[nt * 16 + l16];
#pragma unroll
            for (int rr = 0; rr < 4; ++rr) {
                float hv = gelu_f(cc[rr] + bias);
                h[(quad * 4 + rr) * 264 + nt * 16 + l16] = f2b(hv);
            }
        }
        f32x4 acc = (f32x4){0.f, 0.f, 0.f, 0.f};
#pragma unroll
        for (int c2 = 0; c2 < 8; ++c2) {
            bf16x8 afr = *(bf16x8*)&h[l16 * 264 + c2 * 32 + quad * 8];
            acc = MFMA16(afr, w2f[c2], acc);
        }
#pragma unroll
        for (int rr = 0; rr < 4; ++rr)
            scores[(size_t)(e0 + quad * 4 + rr) * 16 + l16] = acc[rr] + b2r;
    }
}

// ---------- fused per-node segment softmax + weighted aggregation (v2) ----------
// block = node. Fast path (deg<=64): scores cached in LDS (1 HBM sweep), sliced
// bf16x4 V accumulation (4 waves x 64 dims-of-4) + LDS combine. Slow path keeps
// the verified chunked 3-pass structure for deg>64 (prob ~0, correctness only).
__global__ __launch_bounds__(256) void node_agg2(const int* __restrict__ sorted_eid,
                                                 const int* __restrict__ offs,
                                                 const int* __restrict__ srcp,
                                                 const float* __restrict__ scores,
                                                 const short* __restrict__ Vb,
                                                 const float* __restrict__ betap,
                                                 short* __restrict__ accumb,
                                                 float* __restrict__ attn_out) {
    int n = blockIdx.x;
    int beg = offs[n];
    int deg = offs[n + 1] - beg;
    __shared__ float m_s[16], s_s[16];
    __shared__ float red[256];
    __shared__ float w_lds[64 * 8];
    __shared__ float sc_lds[64 * 16];
    __shared__ float red4[4 * 256];
    __shared__ int eid_s[64];
    __shared__ int src_s[64];
    int tid = threadIdx.x;
    int c = tid & 15, j = tid >> 4;
    float beta = *betap;

    if (deg <= 64) {
        // ---- stage eid, src, scores into LDS (single HBM sweep of scores) ----
        if (tid < deg) eid_s[tid] = sorted_eid[beg + tid];
        __syncthreads();
        if (tid < deg) src_s[tid] = srcp[eid_s[tid]];
        for (int i = tid; i < deg * 16; i += 256)
            sc_lds[i] = scores[(size_t)eid_s[i >> 4] * 16 + (i & 15)];
        __syncthreads();

        // ---- per-channel max (from LDS) ----
        float mloc = -INFINITY;
        for (int k = j; k < deg; k += 16) mloc = fmaxf(mloc, sc_lds[k * 16 + c]);
        red[tid] = mloc;
        __syncthreads();
        for (int s = 128; s >= 16; s >>= 1) {
            if (tid < s) red[tid] = fmaxf(red[tid], red[tid + s]);
            __syncthreads();
        }
        if (tid < 16) m_s[tid] = red[tid];
        __syncthreads();

        // ---- per-channel sum of exp (from LDS) ----
        float m = m_s[c];
        float sloc = 0.f;
        for (int k = j; k < deg; k += 16) sloc += __expf(sc_lds[k * 16 + c] - m);
        red[tid] = sloc;
        __syncthreads();
        for (int s = 128; s >= 16; s >>= 1) {
            if (tid < s) red[tid] += red[tid + s];
            __syncthreads();
        }
        if (tid < 16) s_s[tid] = red[tid];
        __syncthreads();

        // ---- weights (from LDS scores) + attn_out write ----
        for (int p = tid; p < deg * 8; p += 256) {
            int k = p >> 3, hh = p & 7;
            float sc1 = sc_lds[k * 16 + 2 * hh];
            float sc2 = sc_lds[k * 16 + 2 * hh + 1];
            float w = __expf(sc1 - m_s[2 * hh]) / s_s[2 * hh]
                    - beta * (__expf(sc2 - m_s[2 * hh + 1]) / s_s[2 * hh + 1]);
            w_lds[k * 8 + hh] = w;
            attn_out[(size_t)eid_s[k] * 8 + hh] = w;
        }
        __syncthreads();

        // ---- sliced accumulate: wave sl handles edges k = sl, sl+4, ... ----
        int sl = tid >> 6, t64 = tid & 63;
        int d0 = t64 * 4, h = t64 >> 3;
        float a0 = 0.f, a1 = 0.f, a2 = 0.f, a3 = 0.f;
        for (int k = sl; k < deg; k += 4) {
            float w = w_lds[k * 8 + h];
            bf16x4 v = *(const bf16x4*)&Vb[(size_t)src_s[k] * 256 + d0];
            a0 += w * b2f(v[0]);
            a1 += w * b2f(v[1]);
            a2 += w * b2f(v[2]);
            a3 += w * b2f(v[3]);
        }
        *(float4*)&red4[sl * 256 + d0] = make_float4(a0, a1, a2, a3);
        __syncthreads();
        float sum = red4[tid] + red4[256 + tid] + red4[512 + tid] + red4[768 + tid];
        accumb[(size_t)n * 256 + tid] = f2b(sum);
        return;
    }

    // ================= slow path (deg > 64): verified chunked 3-pass =================
    float mloc = -INFINITY;
    for (int k = j; k < deg; k += 16) {
        int e = sorted_eid[beg + k];
        mloc = fmaxf(mloc, scores[(size_t)e * 16 + c]);
    }
    red[tid] = mloc;
    __syncthreads();
    for (int s = 128; s >= 16; s >>= 1) {
        if (tid < s) red[tid] = fmaxf(red[tid], red[tid + s]);
        __syncthreads();
    }
    if (tid < 16) m_s[tid] = red[tid];
    __syncthreads();

    float m = m_s[c];
    float sloc = 0.f;
    for (int k = j; k < deg; k += 16) {
        int e = sorted_eid[beg + k];
        sloc += __expf(scores[(size_t)e * 16 + c] - m);
    }
    red[tid] = sloc;
    __syncthreads();
    for (int s = 128; s >= 16; s >>= 1) {
        if (tid < s) red[tid] += red[tid + s];
        __syncthreads();
    }
    if (tid < 16) s_s[tid] = red[tid];
    __syncthreads();

    float acc = 0.f;
    int d = tid, h = d >> 5;
    for (int base = 0; base < deg; base += 64) {
        int nchunk = min(64, deg - base);
        if (tid < nchunk) eid_s[tid] = sorted_eid[beg + base + tid];
        __syncthreads();
        if (tid < nchunk) src_s[tid] = srcp[eid_s[tid]];
        for (int p = tid; p < nchunk * 8; p += 256) {
            int k = p >> 3, hh = p & 7;
            int e = eid_s[k];
            float sc1 = scores[(size_t)e * 16 + 2 * hh];
            float sc2 = scores[(size_t)e * 16 + 2 * hh + 1];
            float w = __expf(sc1 - m_s[2 * hh]) / s_s[2 * hh]
                    - beta * (__expf(sc2 - m_s[2 * hh + 1]) / s_s[2 * hh + 1]);
            w_lds[k * 8 + hh] = w;
            attn_out[(size_t)e * 8 + hh] = w;
        }
        __syncthreads();
        for (int k = 0; k < nchunk; ++k) {
            acc += w_lds[k * 8 + h] * b2f(Vb[(size_t)src_s[k] * 256 + d]);
        }
        __syncthreads();
    }
    accumb[(size_t)n * 256 + d] = f2b(acc);
}

extern "C" void kernel_launch(void* const* d_in, const int* in_sizes, int n_in,
                              void* d_out, int out_size, void* d_ws, size_t ws_size,
                              hipStream_t stream) {
    const float* x         = (const float*)d_in[0];
    const float* edge_attr = (const float*)d_in[1];
    const float* v_w       = (const float*)d_in[2];
    const float* out_w     = (const float*)d_in[3];
    const float* e_w1      = (const float*)d_in[4];
    const float* e_b1      = (const float*)d_in[5];
    const float* e_w2      = (const float*)d_in[6];
    const float* e_b2      = (const float*)d_in[7];
    const float* lq        = (const float*)d_in[8];
    const float* lk        = (const float*)d_in[9];
    const int*   ei        = (const int*)d_in[10];
    const int* srcp = ei;
    const int* tgtp = ei + N_EDGES;

    float* out = (float*)d_out;
    float* attn_out = out + (size_t)N_NODES * 256;
    float* beta_out = attn_out + (size_t)N_EDGES * 8;

    // workspace layout
    short* Vb     = (short*)d_ws;                              // N*256 bf16
    float* scores = (float*)(Vb + (size_t)N_NODES * 256);      // E*16 f32
    short* accumb = (short*)(scores + (size_t)N_EDGES * 16);   // N*256 bf16
    int*   cnt    = (int*)(accumb + (size_t)N_NODES * 256);
    int*   offs   = cnt + N_NODES;
    int*   cursor = offs + N_NODES + 1;
    int*   partials = cursor + N_NODES;
    int*   sorted_eid = partials + 256;
    float* betap  = (float*)(sorted_eid + N_EDGES);

    const int NB = (N_NODES + 255) / 256;

    beta_kernel<<<1, 128, 0, stream>>>(lq, lk, betap, beta_out);

    hipMemsetAsync(cnt, 0, N_NODES * sizeof(int), stream);
    hist_kernel<<<(N_EDGES + 255) / 256, 256, 0, stream>>>(tgtp, cnt);
    scan1<<<NB, 256, 0, stream>>>(cnt, offs, partials, N_NODES);
    scan2<<<1, 256, 0, stream>>>(partials, NB);
    scan3<<<NB, 256, 0, stream>>>(offs, partials, cursor, N_NODES);
    scatter_eid<<<(N_EDGES + 255) / 256, 256, 0, stream>>>(tgtp, cursor, sorted_eid);

    // V(bf16) = x @ v_w.T
    gemm_mfma_t<false, true><<<dim3((N_NODES + 127) / 128, 4), 256, 0, stream>>>(
        x, v_w, Vb, N_NODES);

    // edge MLP -> scores
    edge_mlp_mfma<<<N_EDGES / 256, 256, 0, stream>>>(edge_attr, e_w1, e_b1, e_w2, e_b2,
                                                     scores);

    // fused softmax + aggregation
    node_agg2<<<N_NODES, 256, 0, stream>>>(sorted_eid, offs, srcp, scores, Vb, betap,
                                           accumb, attn_out);

    // out = accum(bf16) @ out_w.T
    gemm_mfma_t<true, false><<<dim3((N_NODES + 127) / 128, 4), 256, 0, stream>>>(
        accumb, out_w, out, N_NODES);
}